// Round 5
// baseline (735.217 us; speedup 1.0000x reference)
//
#include <hip/hip_runtime.h>

// Sizes (fixed by the problem)
#define B 2
#define N 512
#define DIN 256
#define H 16
#define DOUT 128
#define ROWS (B * N)   // 1024

// -------- Kernel A: per row (b*512+n): LN + proj -> a_ws, bq_ws --------
// Single-pass LN: reduce sum(x) and sum(x^2) together -> var = E[x^2] - mu^2.
__global__ __launch_bounds__(256) void kA(const float* __restrict__ feats,
                                          const float* __restrict__ gamma,
                                          const float* __restrict__ beta,
                                          const float* __restrict__ Win,
                                          const float* __restrict__ bin,
                                          float* __restrict__ a_ws,
                                          float* __restrict__ bq_ws) {
    const int row = blockIdx.x;       // 0..1023
    const int t = threadIdx.x;        // 0..255

    __shared__ float sx[DIN];         // normalized row
    __shared__ float pp[256];         // proj partials
    __shared__ float redA[4], redB[4];

    const float x = feats[row * DIN + t];

    float s = x;
    float s2 = x * x;
#pragma unroll
    for (int o = 32; o; o >>= 1) {
        s  += __shfl_xor(s,  o, 64);
        s2 += __shfl_xor(s2, o, 64);
    }
    if ((t & 63) == 0) { redA[t >> 6] = s; redB[t >> 6] = s2; }
    __syncthreads();
    const float mean = (redA[0] + redA[1] + redA[2] + redA[3]) * (1.0f / 256.0f);
    const float ex2  = (redB[0] + redB[1] + redB[2] + redB[3]) * (1.0f / 256.0f);
    const float var  = ex2 - mean * mean;
    const float rstd = rsqrtf(var + 1e-5f);

    const float xn = (x - mean) * rstd * gamma[t] + beta[t];
    sx[t] = xn;
    __syncthreads();

    // ---- proj = xn @ Win (+ bin): 256 threads, k = t&31, seg = t>>5 ----
    {
        const int k = t & 31;
        const int seg = t >> 5;       // 8 segments of 32 j each
        const int j0 = seg * 32;
        float partial = 0.0f;
#pragma unroll
        for (int j = 0; j < 32; j++) {
            partial = fmaf(sx[j0 + j], Win[(j0 + j) * 32 + k], partial);
        }
        pp[t] = partial;
    }
    __syncthreads();

    if (t < 32) {
        float pr = bin[t];
#pragma unroll
        for (int h = 0; h < 8; h++) pr += pp[h * 32 + t];
        if (t < H) a_ws[row * H + t] = pr;             // a  -> workspace
        else bq_ws[row * H + (t - H)] = pr;            // bq -> workspace
    }
}

// -------- Kernel B (R3 structure, plain stores): --------
// out[row][m][d] = b_out[d] + sum_q T[d][q]*bq[b,m][q]
// grid: 1024 blocks = one per row, 256 threads.
// Phase 0: T computed in-block from a[row] + Wout, stored transposed in LDS
//          Tt[q][d] (conflict-free b128 gather).
// Phase 1: bq staged in 2 chunks of 256 m-rows (16 KB); stream loop.
// LDS = 24.25 KB. Low register footprint (no cross-phase staging registers) —
// R4 showed holding stage[8] across the Tr gather spills at the 128-VGPR cap.
// STORES ARE PLAIN (not nontemporal): the harness fill kernel sustains
// 6.4 TB/s with plain stores; nt bypasses L2 so both steady-state retirement
// and the mid-stream barrier's vmcnt(0) drain wait on HBM (~900cy) instead of
// L2 (~200cy). Output is write-once; L2 pollution costs nothing we re-read.
__global__ __launch_bounds__(256, 4) void kB(const float* __restrict__ a_ws,
                                             const float* __restrict__ bq_ws,
                                             const float* __restrict__ Wout,
                                             const float* __restrict__ bout,
                                             float* __restrict__ out) {
    const int row = blockIdx.x;           // b*512 + n
    const int bb = row >> 9;              // batch
    const int t = threadIdx.x;

    __shared__ float Tt[H][DOUT];         // transposed T: 16 x 128 fp32 = 8 KB
    __shared__ float sbq[256 * H];        // 256 m-rows x 16 fp32 = 16 KB

    // ---- a[row]: block-uniform address -> scalar broadcast ----
    const float* arow = a_ws + row * H;
    float a_[H];
#pragma unroll
    for (int p = 0; p < H; p++) a_[p] = arow[p];

    // ---- T[d][q] = sum_p a[p] * Wout[d*256 + p*16 + q], thread: d=t>>1, q-half ----
    {
        const int d = t >> 1;
        const int q0 = (t & 1) * 8;
        float acc[8];
#pragma unroll
        for (int j = 0; j < 8; j++) acc[j] = 0.0f;
        const float* wp = Wout + d * 256 + q0;
#pragma unroll
        for (int p = 0; p < H; p++) {
            const float av = a_[p];
            const float4* w4 = reinterpret_cast<const float4*>(wp + p * 16);
            const float4 w0 = w4[0], w1 = w4[1];
            acc[0] = fmaf(av, w0.x, acc[0]);
            acc[1] = fmaf(av, w0.y, acc[1]);
            acc[2] = fmaf(av, w0.z, acc[2]);
            acc[3] = fmaf(av, w0.w, acc[3]);
            acc[4] = fmaf(av, w1.x, acc[4]);
            acc[5] = fmaf(av, w1.y, acc[5]);
            acc[6] = fmaf(av, w1.z, acc[6]);
            acc[7] = fmaf(av, w1.w, acc[7]);
        }
        // transposed store: 2-way bank aliasing only (free)
#pragma unroll
        for (int j = 0; j < 8; j++) Tt[q0 + j][d] = acc[j];
    }
    __syncthreads();

    // ---- gather my Tr[4][16]: 16x conflict-free ds_read_b128 ----
    const int d0 = (t & 31) * 4;
    const int ml = t >> 5;
    float Tr[4][16];
#pragma unroll
    for (int q = 0; q < H; q++) {
        const float4 u = *reinterpret_cast<const float4*>(&Tt[q][d0]);
        Tr[0][q] = u.x;
        Tr[1][q] = u.y;
        Tr[2][q] = u.z;
        Tr[3][q] = u.w;
    }

    float bo[4];
#pragma unroll
    for (int i = 0; i < 4; i++) bo[i] = bout[d0 + i];

    const float* bq_base = bq_ws + (size_t)bb * (N * H);
    float* out_base = out + (size_t)row * (N * DOUT) + d0;

#pragma unroll
    for (int half = 0; half < 2; half++) {
        __syncthreads();   // protect sbq against previous chunk's readers
        // stage 256 m-rows: 1024 float4, 4 per thread, coalesced
        {
            const float4* src = reinterpret_cast<const float4*>(bq_base + half * (256 * H));
            float4* dst = reinterpret_cast<float4*>(sbq);
#pragma unroll
            for (int i = 0; i < 4; i++) dst[i * 256 + t] = src[i * 256 + t];
        }
        __syncthreads();

#pragma unroll 4
        for (int k = 0; k < 32; k++) {
            const int ml_ = k * 8 + ml;   // 0..255 within chunk
            const float4* bqv = reinterpret_cast<const float4*>(&sbq[ml_ * H]);
            const float4 q0 = bqv[0], q1 = bqv[1], q2 = bqv[2], q3 = bqv[3];
            const float bv[16] = {q0.x, q0.y, q0.z, q0.w, q1.x, q1.y, q1.z, q1.w,
                                  q2.x, q2.y, q2.z, q2.w, q3.x, q3.y, q3.z, q3.w};

            float acc[4] = {bo[0], bo[1], bo[2], bo[3]};
#pragma unroll
            for (int q = 0; q < H; q++) {
#pragma unroll
                for (int i = 0; i < 4; i++) acc[i] = fmaf(bv[q], Tr[i][q], acc[i]);
            }

            float4* dst = reinterpret_cast<float4*>(out_base + (size_t)(half * 256 + ml_) * DOUT);
            *dst = make_float4(acc[0], acc[1], acc[2], acc[3]);
        }
    }
}

extern "C" void kernel_launch(void* const* d_in, const int* in_sizes, int n_in,
                              void* d_out, int out_size, void* d_ws, size_t ws_size,
                              hipStream_t stream) {
    const float* feats = (const float*)d_in[0];
    const float* gamma = (const float*)d_in[1];
    const float* beta  = (const float*)d_in[2];
    const float* Win   = (const float*)d_in[3];
    const float* bin   = (const float*)d_in[4];
    const float* Wout  = (const float*)d_in[5];
    const float* bout  = (const float*)d_in[6];

    float* a_ws  = (float*)d_ws;                                  // ROWS*16 fp32 = 64 KB
    float* bq_ws = (float*)((char*)d_ws + 64 * 1024);             // ROWS*16 fp32 = 64 KB

    kA<<<ROWS, 256, 0, stream>>>(feats, gamma, beta, Win, bin, a_ws, bq_ws);
    kB<<<ROWS, 256, 0, stream>>>(a_ws, bq_ws, Wout, bout, (float*)d_out);
}

// Round 6
// 294.266 us; speedup vs baseline: 2.4985x; 2.4985x over previous
//
#include <hip/hip_runtime.h>

// Sizes (fixed by the problem)
#define B 2
#define N 512
#define DIN 256
#define H 16
#define DOUT 128
#define ROWS (B * N)   // 1024

typedef float f4 __attribute__((ext_vector_type(4)));  // clang vector: valid for nontemporal builtins

// -------- Kernel A: per row (b*512+n): LN + proj -> a_ws, bq_ws --------
// Single-pass LN: reduce sum(x) and sum(x^2) together -> var = E[x^2] - mu^2.
__global__ __launch_bounds__(256) void kA(const float* __restrict__ feats,
                                          const float* __restrict__ gamma,
                                          const float* __restrict__ beta,
                                          const float* __restrict__ Win,
                                          const float* __restrict__ bin,
                                          float* __restrict__ a_ws,
                                          float* __restrict__ bq_ws) {
    const int row = blockIdx.x;       // 0..1023
    const int t = threadIdx.x;        // 0..255

    __shared__ float sx[DIN];         // normalized row
    __shared__ float pp[256];         // proj partials
    __shared__ float redA[4], redB[4];

    const float x = feats[row * DIN + t];

    float s = x;
    float s2 = x * x;
#pragma unroll
    for (int o = 32; o; o >>= 1) {
        s  += __shfl_xor(s,  o, 64);
        s2 += __shfl_xor(s2, o, 64);
    }
    if ((t & 63) == 0) { redA[t >> 6] = s; redB[t >> 6] = s2; }
    __syncthreads();
    const float mean = (redA[0] + redA[1] + redA[2] + redA[3]) * (1.0f / 256.0f);
    const float ex2  = (redB[0] + redB[1] + redB[2] + redB[3]) * (1.0f / 256.0f);
    const float var  = ex2 - mean * mean;
    const float rstd = rsqrtf(var + 1e-5f);

    const float xn = (x - mean) * rstd * gamma[t] + beta[t];
    sx[t] = xn;
    __syncthreads();

    // ---- proj = xn @ Win (+ bin): 256 threads, k = t&31, seg = t>>5 ----
    {
        const int k = t & 31;
        const int seg = t >> 5;       // 8 segments of 32 j each
        const int j0 = seg * 32;
        float partial = 0.0f;
#pragma unroll
        for (int j = 0; j < 32; j++) {
            partial = fmaf(sx[j0 + j], Win[(j0 + j) * 32 + k], partial);
        }
        pp[t] = partial;
    }
    __syncthreads();

    if (t < 32) {
        float pr = bin[t];
#pragma unroll
        for (int h = 0; h < 8; h++) pr += pp[h * 32 + t];
        if (t < H) a_ws[row * H + t] = pr;             // a  -> workspace
        else bq_ws[row * H + (t - H)] = pr;            // bq -> workspace
    }
}

// -------- Kernel B: out[row][m][d] = b_out[d] + sum_q T[d][q]*bq[b,m][q] --------
// grid: 1024 blocks = one per row, 256 threads.
//
// NT STORES ARE MANDATORY (R5 evidence: plain stores -> kB 507us, FETCH 1.28GB
// of L2 refetch/RFO traffic, WRITE 429MB vs 268MB output. nt bypasses L2 and
// streams at fill-kernel rates.)
//
// Stage-once structure with DISJOINT LDS (vs R4's aliased version that spilled):
//   Tt[16][128] (8 KB) + sbq[512*16] (32 KB) = 40.25 KB.
// Order: issue 8 bq stage loads -> T compute (hides load latency) ->
// write stage->LDS (stage regs DIE here, before Tr[4][16] is born -> peak
// VGPR < 128, unlike R4 where stage[] was live across the Tr gather) ->
// ONE barrier -> Tr gather -> 64-iter stream with no barriers, no vmem loads.
__global__ __launch_bounds__(256, 4) void kB(const float* __restrict__ a_ws,
                                             const float* __restrict__ bq_ws,
                                             const float* __restrict__ Wout,
                                             const float* __restrict__ bout,
                                             float* __restrict__ out) {
    const int row = blockIdx.x;           // b*512 + n
    const int bb = row >> 9;              // batch
    const int t = threadIdx.x;

    __shared__ float Tt[H][DOUT];         // transposed T: 16 x 128 fp32 = 8 KB
    __shared__ alignas(16) float sbq[N * H];  // whole-batch bq: 32 KB

    // ---- issue bq stage loads FIRST; latency hides under T compute ----
    float4 stage[8];
    {
        const float4* src = reinterpret_cast<const float4*>(bq_ws + (size_t)bb * (N * H));
#pragma unroll
        for (int i = 0; i < 8; i++) stage[i] = src[i * 256 + t];
    }

    // ---- a[row]: block-uniform address -> scalar broadcast ----
    const float* arow = a_ws + row * H;
    float a_[H];
#pragma unroll
    for (int p = 0; p < H; p++) a_[p] = arow[p];

    // ---- T[d][q] = sum_p a[p] * Wout[d*256 + p*16 + q], thread: d=t>>1, q-half ----
    {
        const int d = t >> 1;
        const int q0 = (t & 1) * 8;
        float acc[8];
#pragma unroll
        for (int j = 0; j < 8; j++) acc[j] = 0.0f;
        const float* wp = Wout + d * 256 + q0;
#pragma unroll
        for (int p = 0; p < H; p++) {
            const float av = a_[p];
            const float4* w4 = reinterpret_cast<const float4*>(wp + p * 16);
            const float4 w0 = w4[0], w1 = w4[1];
            acc[0] = fmaf(av, w0.x, acc[0]);
            acc[1] = fmaf(av, w0.y, acc[1]);
            acc[2] = fmaf(av, w0.z, acc[2]);
            acc[3] = fmaf(av, w0.w, acc[3]);
            acc[4] = fmaf(av, w1.x, acc[4]);
            acc[5] = fmaf(av, w1.y, acc[5]);
            acc[6] = fmaf(av, w1.z, acc[6]);
            acc[7] = fmaf(av, w1.w, acc[7]);
        }
        // transposed store: bank = d%32, 2 lanes/bank -> free
#pragma unroll
        for (int j = 0; j < 8; j++) Tt[q0 + j][d] = acc[j];
    }

    // ---- write staged bq to LDS (stage registers die here) ----
    {
        float4* dst = reinterpret_cast<float4*>(sbq);
#pragma unroll
        for (int i = 0; i < 8; i++) dst[i * 256 + t] = stage[i];
    }

    __syncthreads();   // the ONLY barrier: all Tt + sbq writes -> all reads

    // ---- gather my Tr[4][16]: 16x conflict-free ds_read_b128 ----
    const int d0 = (t & 31) * 4;
    const int ml = t >> 5;
    float Tr[4][16];
#pragma unroll
    for (int q = 0; q < H; q++) {
        const float4 u = *reinterpret_cast<const float4*>(&Tt[q][d0]);
        Tr[0][q] = u.x;
        Tr[1][q] = u.y;
        Tr[2][q] = u.z;
        Tr[3][q] = u.w;
    }

    float bo[4];
#pragma unroll
    for (int i = 0; i < 4; i++) bo[i] = bout[d0 + i];

    // ---- stream: 64 iters, no barriers, no vmem loads, nt stores only ----
    float* out_base = out + (size_t)row * (N * DOUT) + d0;

#pragma unroll 4
    for (int k = 0; k < 64; k++) {
        const int m = k * 8 + ml;
        const float4* bqv = reinterpret_cast<const float4*>(&sbq[m * H]);
        const float4 q0 = bqv[0], q1 = bqv[1], q2 = bqv[2], q3 = bqv[3];
        const float bv[16] = {q0.x, q0.y, q0.z, q0.w, q1.x, q1.y, q1.z, q1.w,
                              q2.x, q2.y, q2.z, q2.w, q3.x, q3.y, q3.z, q3.w};

        float acc[4] = {bo[0], bo[1], bo[2], bo[3]};
#pragma unroll
        for (int q = 0; q < H; q++) {
#pragma unroll
            for (int i = 0; i < 4; i++) acc[i] = fmaf(bv[q], Tr[i][q], acc[i]);
        }

        f4 val = {acc[0], acc[1], acc[2], acc[3]};
        f4* dst = reinterpret_cast<f4*>(out_base + (size_t)m * DOUT);
        __builtin_nontemporal_store(val, dst);
    }
}

extern "C" void kernel_launch(void* const* d_in, const int* in_sizes, int n_in,
                              void* d_out, int out_size, void* d_ws, size_t ws_size,
                              hipStream_t stream) {
    const float* feats = (const float*)d_in[0];
    const float* gamma = (const float*)d_in[1];
    const float* beta  = (const float*)d_in[2];
    const float* Win   = (const float*)d_in[3];
    const float* bin   = (const float*)d_in[4];
    const float* Wout  = (const float*)d_in[5];
    const float* bout  = (const float*)d_in[6];

    float* a_ws  = (float*)d_ws;                                  // ROWS*16 fp32 = 64 KB
    float* bq_ws = (float*)((char*)d_ws + 64 * 1024);             // ROWS*16 fp32 = 64 KB

    kA<<<ROWS, 256, 0, stream>>>(feats, gamma, beta, Win, bin, a_ws, bq_ws);
    kB<<<ROWS, 256, 0, stream>>>(a_ws, bq_ws, Wout, bout, (float*)d_out);
}